// Round 18
// baseline (205.435 us; speedup 1.0000x reference)
//
#include <hip/hip_runtime.h>
#include <hip/hip_bf16.h>

#define B_   2
#define T_   2048
#define D_   2048
#define NH_  16
#define NKV_ 4
#define HD_  128
#define KD_  512   // NKV*HD
#define BT_  4096  // B_*T_

typedef __bf16 bf16x8 __attribute__((ext_vector_type(8)));
typedef float  f32x4  __attribute__((ext_vector_type(4)));
typedef float  f32x16 __attribute__((ext_vector_type(16)));

__device__ __forceinline__ void gload_lds16(const __hip_bfloat16* g, __hip_bfloat16* l) {
    __builtin_amdgcn_global_load_lds(
        (__attribute__((address_space(1))) void*)(g),
        (__attribute__((address_space(3))) void*)(l),
        16, 0, 0);
}

// ---------------- fp32 -> bf16 convert (all 5 tensors, one launch) ----------------
__global__ void f2b_all(const float4* __restrict__ x,  const float4* __restrict__ wq,
                        const float4* __restrict__ wk, const float4* __restrict__ wv,
                        const float4* __restrict__ wp,
                        ushort4* __restrict__ xb,  ushort4* __restrict__ wqb,
                        ushort4* __restrict__ wkb, ushort4* __restrict__ wvb,
                        ushort4* __restrict__ wpb) {
    const int e0 = BT_ * D_ / 4;
    const int e1 = e0 + D_ * D_ / 4;
    const int e2 = e1 + KD_ * D_ / 4;
    const int e3 = e2 + KD_ * D_ / 4;
    const int e4 = e3 + D_ * D_ / 4;
    int idx = blockIdx.x * blockDim.x + threadIdx.x;
    int stride = gridDim.x * blockDim.x;
    for (int j = idx; j < e4; j += stride) {
        const float4* src; ushort4* dst; int off;
        if      (j < e0) { src = x;  dst = xb;  off = j; }
        else if (j < e1) { src = wq; dst = wqb; off = j - e0; }
        else if (j < e2) { src = wk; dst = wkb; off = j - e1; }
        else if (j < e3) { src = wv; dst = wvb; off = j - e2; }
        else             { src = wp; dst = wpb; off = j - e3; }
        float4 v = src[off];
        __hip_bfloat16 a = __float2bfloat16(v.x), b = __float2bfloat16(v.y),
                       c = __float2bfloat16(v.z), d = __float2bfloat16(v.w);
        ushort4 o;
        o.x = *(const unsigned short*)&a; o.y = *(const unsigned short*)&b;
        o.z = *(const unsigned short*)&c; o.w = *(const unsigned short*)&d;
        dst[off] = o;
    }
}

// ====== pipelined 128x128 GEMM main loop (depth-2 counted vmcnt, 3 LDS slots) ======
// RACE FIX (rule #18 / m152): the end-of-iter barrier MUST be a real LDS fence.
// A bare s_barrier builtin is not a memory barrier to LLVM -> ds_reads could sink
// past it; with 3 slots the read slot is re-targeted by another wave's DMA one
// barrier later -> intermittent corruption (R17 flake). The fence below pins all
// LDS-read issue AND completion (lgkmcnt(0)) before any wave crosses the barrier.
#define GEMM_PIPE(Aptr, Bptr, ROWB, colL, K)                                                  \
    const int tid = threadIdx.x, w = tid >> 6, lane = tid & 63;                               \
    const int lr = lane & 15, lk = lane >> 4;                                                 \
    const int wr = w >> 1, wc = w & 1;                                                        \
    const int lksw = lk ^ (lr & 3);                                                           \
    const size_t row0 = (size_t)(ROWB) * 128;                                                 \
    const int schunk = (tid % 4) ^ ((tid / 4) & 3);                                           \
    const __hip_bfloat16* ga = (Aptr) + (row0 + tid / 4) * (K) + schunk * 8;                  \
    const __hip_bfloat16* gb = (Bptr) + ((size_t)(colL) + tid / 4) * (K) + schunk * 8;        \
    const int KI = (K) >> 5;                                                                  \
    auto stage = [&](int u, int slot) {                                                       \
        int uu = u < KI ? u : KI - 1;                                                         \
        const int kk = uu * 32;                                                               \
        gload_lds16(ga + kk,                  &As[slot][w * 512]);                            \
        gload_lds16(ga + kk + (size_t)64*(K), &As[slot][2048 + w * 512]);                     \
        gload_lds16(gb + kk,                  &Bs[slot][w * 512]);                            \
        gload_lds16(gb + kk + (size_t)64*(K), &Bs[slot][2048 + w * 512]);                     \
    };                                                                                        \
    f32x4 acc[4][4] = {};                                                                     \
    stage(0, 0); stage(1, 1);                                                                 \
    int sstage = 2, scomp = 0;                                                                \
    for (int kt = 0; kt < KI; ++kt) {                                                         \
        stage(kt + 2, sstage);                                                                \
        asm volatile("s_waitcnt vmcnt(8)" ::: "memory");                                      \
        __builtin_amdgcn_s_barrier();                                                         \
        __builtin_amdgcn_sched_barrier(0);                                                    \
        bf16x8 af[4], bfr[4];                                                                 \
        _Pragma("unroll")                                                                     \
        for (int m = 0; m < 4; m++)                                                           \
            af[m] = *(const bf16x8*)&As[scomp][(wr * 64 + m * 16 + lr) * 32 + lksw * 8];      \
        _Pragma("unroll")                                                                     \
        for (int n = 0; n < 4; n++)                                                           \
            bfr[n] = *(const bf16x8*)&Bs[scomp][(wc * 64 + n * 16 + lr) * 32 + lksw * 8];     \
        _Pragma("unroll")                                                                     \
        for (int m = 0; m < 4; m++)                                                           \
            _Pragma("unroll")                                                                 \
            for (int n = 0; n < 4; n++)                                                       \
                acc[m][n] = __builtin_amdgcn_mfma_f32_16x16x32_bf16(af[m], bfr[n],            \
                                                                    acc[m][n], 0, 0, 0);      \
        asm volatile("s_waitcnt lgkmcnt(0)" ::: "memory");  /* LDS reads fully done */        \
        __builtin_amdgcn_sched_barrier(0);                                                    \
        __builtin_amdgcn_s_barrier();   /* end-of-iter: slot scomp now reusable */            \
        sstage = (sstage == 2) ? 0 : sstage + 1;                                              \
        scomp  = (scomp  == 2) ? 0 : scomp  + 1;                                              \
    }

// Fused q/k/v projection + RMSNorm + RoPE + gain + bf16 + fragment layouts.
// Each 128-col tile is exactly one head (HD=128) -> norm reduction is block-local.
__global__ __launch_bounds__(256, 3)
void gemm_qkv(const __hip_bfloat16* __restrict__ A,
              const __hip_bfloat16* __restrict__ Wq, const __hip_bfloat16* __restrict__ Wk,
              const __hip_bfloat16* __restrict__ Wv, const float* __restrict__ qg,
              __hip_bfloat16* __restrict__ qbb, __hip_bfloat16* __restrict__ kfb,
              __hip_bfloat16* __restrict__ vfb) {
    __shared__ __attribute__((aligned(16))) __hip_bfloat16 As[3][4096];
    __shared__ __attribute__((aligned(16))) __hip_bfloat16 Bs[3][4096];
    const int cb   = blockIdx.y;                  // 0..23: col-block (head)
    const int rowb = blockIdx.x;                  // 0..31: row-block
    const __hip_bfloat16* Bw;
    if (cb < 16)      Bw = Wq + (size_t)cb * 128 * D_;
    else if (cb < 20) Bw = Wk + (size_t)(cb - 16) * 128 * D_;
    else              Bw = Wv + (size_t)(cb - 20) * 128 * D_;

    GEMM_PIPE(A, Bw, rowb, 0, D_)

    // drain trailing staging DMAs before reusing As as the reduction buffer
    asm volatile("s_waitcnt vmcnt(0)" ::: "memory");
    __syncthreads();
    float* Red = (float*)&As[0][0];   // [2][128] partial sums

    if (cb < 20) {
        // ---- RMSNorm: row sum of squares over 128 cols ----
        float ssp[16];
        #pragma unroll
        for (int m = 0; m < 4; m++)
            #pragma unroll
            for (int r = 0; r < 4; r++) {
                float v = 0.f;
                #pragma unroll
                for (int n = 0; n < 4; n++) v += acc[m][n][r] * acc[m][n][r];
                #pragma unroll
                for (int off = 1; off < 16; off <<= 1) v += __shfl_xor(v, off);
                ssp[m * 4 + r] = v;
            }
        if (lr == 0) {
            #pragma unroll
            for (int m = 0; m < 4; m++)
                #pragma unroll
                for (int r = 0; r < 4; r++)
                    Red[wc * 128 + wr * 64 + m * 16 + lk * 4 + r] = ssp[m * 4 + r];
        }
        __syncthreads();
        #pragma unroll
        for (int m = 0; m < 4; m++)
            #pragma unroll
            for (int r = 0; r < 4; r++) {
                float tot = ssp[m * 4 + r] + Red[(wc ^ 1) * 128 + wr * 64 + m * 16 + lk * 4 + r];
                float rn = rsqrtf(tot * (1.0f / HD_) + 1.1920929e-7f);
                #pragma unroll
                for (int n = 0; n < 4; n++) acc[m][n][r] *= rn;
            }
        // ---- partial RoPE on dims 0..15 (cols 0..15 live in wc==0, n==0, d=lr) ----
        if (wc == 0) {
            float invf = exp2f(-(float)(lr & 7) * 1.66096404744368f);
            #pragma unroll
            for (int m = 0; m < 4; m++)
                #pragma unroll
                for (int r = 0; r < 4; r++) {
                    int t = (int)((row0 + wr * 64 + m * 16 + lk * 4 + r) & (T_ - 1));
                    float f = (float)t * invf;
                    float sn, cs;
                    sincosf(f, &sn, &cs);
                    float y  = acc[m][0][r];
                    float yp = __shfl_xor(y, 8);
                    acc[m][0][r] = (lr < 8) ? (y * cs + yp * sn) : (-y * cs + yp * sn);
                }
        }
    }

    if (cb < 16) {
        // q: gain * 1/sqrt(HD) * log2(e), layout [b][h][t][hd]
        float g = qg[cb] * 0.1275174305f;
        #pragma unroll
        for (int m = 0; m < 4; m++)
            #pragma unroll
            for (int r = 0; r < 4; r++) {
                size_t bt = row0 + wr * 64 + m * 16 + lk * 4 + r;
                int b = (int)(bt >> 11), t = (int)(bt & (T_ - 1));
                __hip_bfloat16* dst = qbb + ((size_t)(b * NH_ + cb) * T_ + t) * HD_;
                #pragma unroll
                for (int n = 0; n < 4; n++) {
                    int d = wc * 64 + n * 16 + lr;
                    dst[d] = __float2bfloat16(acc[m][n][r] * g);
                }
            }
    } else if (cb < 20) {
        // k: fragment layout  ((t>>5)*8+(d>>4))*2+((d>>3)&1))*256 + (t&31)*8 + (d&7)
        int kv = cb - 16;
        #pragma unroll
        for (int m = 0; m < 4; m++)
            #pragma unroll
            for (int r = 0; r < 4; r++) {
                size_t bt = row0 + wr * 64 + m * 16 + lk * 4 + r;
                int b = (int)(bt >> 11), t = (int)(bt & (T_ - 1));
                __hip_bfloat16* base = kfb + (size_t)(b * NKV_ + kv) * T_ * HD_;
                #pragma unroll
                for (int n = 0; n < 4; n++) {
                    int d = wc * 64 + n * 16 + lr;
                    size_t idx2 = (size_t)((((t >> 5) * 8 + (d >> 4)) * 2 + ((d >> 3) & 1))) * 256
                               + (t & 31) * 8 + (d & 7);
                    base[idx2] = __float2bfloat16(acc[m][n][r]);
                }
            }
    } else {
        // v: fragment layout  ((((t>>5)*4+(d>>5))*4+((t>>3)&3))*32+(d&31))*8 + (t&7)
        int kv = cb - 20;
        #pragma unroll
        for (int m = 0; m < 4; m++)
            #pragma unroll
            for (int r = 0; r < 4; r++) {
                size_t bt = row0 + wr * 64 + m * 16 + lk * 4 + r;
                int b = (int)(bt >> 11), t = (int)(bt & (T_ - 1));
                __hip_bfloat16* base = vfb + (size_t)(b * NKV_ + kv) * T_ * HD_;
                #pragma unroll
                for (int n = 0; n < 4; n++) {
                    int d = wc * 64 + n * 16 + lr;
                    size_t idx2 = (size_t)(((((t >> 5) * 4 + (d >> 5)) * 4 + ((t >> 3) & 3)) * 32
                               + (d & 31))) * 8 + (t & 7);
                    base[idx2] = __float2bfloat16(acc[m][n][r]);
                }
            }
    }
}

// Plain pipelined GEMM (output projection), f32 out
__global__ __launch_bounds__(256, 3)
void gemm_p(const __hip_bfloat16* __restrict__ A, const __hip_bfloat16* __restrict__ B,
            float* __restrict__ C, int N, int K) {
    __shared__ __attribute__((aligned(16))) __hip_bfloat16 As[3][4096];
    __shared__ __attribute__((aligned(16))) __hip_bfloat16 Bs[3][4096];
    const int colL = blockIdx.y * 128;
    GEMM_PIPE(A, B, blockIdx.x, colL, K)
    #pragma unroll
    for (int m = 0; m < 4; m++)
        #pragma unroll
        for (int n = 0; n < 4; n++)
            #pragma unroll
            for (int r = 0; r < 4; r++)
                C[(row0 + wr * 64 + m * 16 + lk * 4 + r) * (size_t)N
                  + colL + wc * 64 + n * 16 + lr] = acc[m][n][r];
}

// ---------------- causal GQA flash attention (R9 kernel, fragment-direct) ----------------
__device__ __forceinline__ unsigned pkbf(float a, float b) {
    __hip_bfloat16 x = __float2bfloat16(a), y = __float2bfloat16(b);
    unsigned short xu = *(const unsigned short*)&x, yu = *(const unsigned short*)&y;
    return (unsigned)xu | ((unsigned)yu << 16);
}

union U8u { unsigned u[4]; bf16x8 v; };

__global__ __launch_bounds__(512, 2)
void attn_fwd(const __hip_bfloat16* __restrict__ qb, const __hip_bfloat16* __restrict__ kfb,
              const __hip_bfloat16* __restrict__ vfb, __hip_bfloat16* __restrict__ yb) {
    __shared__ float Mrg[4][4224];   // per-head merge region: 4096 O + 64 m + 64 s
    const int tid  = threadIdx.x;
    const int w    = tid >> 6, lane = tid & 63;
    const int l31  = lane & 31, hi = lane >> 5;
    const int hd4  = w & 3;                // head within kv group
    const int seg  = w >> 2;               // KV segment 0/1
    const int bid  = blockIdx.x;
    const int strm = bid & 7;              // = b*4 + kvh (XCD-grouped K/V stream)
    const int b    = strm >> 2, kvh = strm & 3;
    const int idx  = bid >> 3;             // 0..63
    const int c    = (idx < 32) ? (63 - 2 * idx) : (126 - 2 * idx);
    const int ns   = (c >> 1) + 1;         // iters per segment
    const int h    = kvh * 4 + hd4;
    const int qa   = c * 32;

    const __hip_bfloat16* qp  = qb  + ((size_t)(b * NH_ + h) * T_ + qa) * HD_;
    const __hip_bfloat16* kfp = kfb + (size_t)(b * NKV_ + kvh) * T_ * HD_ + lane * 8;
    const __hip_bfloat16* vfp = vfb + (size_t)(b * NKV_ + kvh) * T_ * HD_ + lane * 8;

    bf16x8 qfr[8];
    #pragma unroll
    for (int hb = 0; hb < 8; ++hb)
        qfr[hb] = *(const bf16x8*)(qp + (size_t)l31 * HD_ + hb * 16 + hi * 8);

    f32x16 o0 = {}, o1 = {}, o2 = {}, o3 = {};
    float m = -1e30f, s = 0.f;

    bf16x8 kk[8], vv[8];
    {   // prologue: load K fragments of this segment's first tile
        int kt0 = seg ? (ns <= c ? ns : c) : 0;
        #pragma unroll
        for (int hb = 0; hb < 8; ++hb)
            kk[hb] = *(const bf16x8*)(kfp + ((size_t)kt0 * 16 + hb * 2) * 256);
    }

    for (int t = 0; t < ns; ++t) {
        __builtin_amdgcn_s_barrier();      // keep the 4 head-waves tile-aligned for L1 reuse

        const int kt_raw = seg ? ns + t : t;
        const bool dead  = kt_raw > c;
        const int kt     = dead ? c : kt_raw;

        // issue V(kt) fragment loads early (consumed after QK+softmax)
        #pragma unroll
        for (int db = 0; db < 4; ++db) {
            vv[db * 2]     = *(const bf16x8*)(vfp + ((size_t)kt * 16 + db * 4) * 256);
            vv[db * 2 + 1] = *(const bf16x8*)(vfp + ((size_t)kt * 16 + db * 4) * 256 + 512);
        }

        // S^T[kv][q] = sum_hd K[kv][hd] * Q[q][hd]
        f32x16 sa = {};
        __builtin_amdgcn_s_setprio(1);
        #pragma unroll
        for (int hb = 0; hb < 8; ++hb)
            sa = __builtin_amdgcn_mfma_f32_32x32x16_bf16(kk[hb], qfr[hb], sa, 0, 0, 0);
        __builtin_amdgcn_s_setprio(0);

        // prefetch K(next tile) into kk (hidden under softmax + PV)
        {
            int ktn_r = (seg ? ns : 0) + t + 1;
            int ktn = ktn_r > c ? c : ktn_r;
            #pragma unroll
            for (int hb = 0; hb < 8; ++hb)
                kk[hb] = *(const bf16x8*)(kfp + ((size_t)ktn * 16 + hb * 2) * 256);
        }

        if (dead) {
            #pragma unroll
            for (int r = 0; r < 16; ++r) sa[r] = -1e30f;
        } else if (kt == c) {  // diagonal tile: mask kv > q (relative indices)
            #pragma unroll
            for (int r = 0; r < 16; ++r) {
                int kvrel = (r & 3) + 8 * (r >> 2) + 4 * hi;
                if (kvrel > l31) sa[r] = -1e30f;
            }
        }
        float pm = sa[0];
        #pragma unroll
        for (int r = 1; r < 16; ++r) pm = fmaxf(pm, sa[r]);
        pm = fmaxf(pm, __shfl_xor(pm, 32));
        if (!__all(pm <= m + 8.f)) {   // deferred rescale (THR=8, log2 domain)
            float mn = fmaxf(m, pm);
            float corr = exp2f(m - mn);
            s *= corr;
            #pragma unroll
            for (int r = 0; r < 16; ++r) { o0[r] *= corr; o1[r] *= corr; o2[r] *= corr; o3[r] *= corr; }
            m = mn;
        }
        float p[16]; float rs = 0.f;
        #pragma unroll
        for (int r = 0; r < 16; ++r) { p[r] = exp2f(sa[r] - m); rs += p[r]; }
        rs += __shfl_xor(rs, 32);
        s += rs;
        // pack P -> bf16 PV B-fragments (lane pair l <-> l^32 exchange)
        unsigned pk[8];
        #pragma unroll
        for (int jj = 0; jj < 8; ++jj) pk[jj] = pkbf(p[2 * jj], p[2 * jj + 1]);
        unsigned pks[8];
        #pragma unroll
        for (int jj = 0; jj < 8; ++jj) pks[jj] = (unsigned)__shfl_xor((int)pk[jj], 32);
        U8u pa0, pa1;
        pa0.u[0] = hi ? pks[2] : pk[0];
        pa0.u[1] = hi ? pks[3] : pk[1];
        pa0.u[2] = hi ? pk[2]  : pks[0];
        pa0.u[3] = hi ? pk[3]  : pks[1];
        pa1.u[0] = hi ? pks[6] : pk[4];
        pa1.u[1] = hi ? pks[7] : pk[5];
        pa1.u[2] = hi ? pk[6]  : pks[4];
        pa1.u[3] = hi ? pk[7]  : pks[5];
        // O^T[d][q] += V^T[d][kv] * P[kv][q]
        __builtin_amdgcn_s_setprio(1);
        o0 = __builtin_amdgcn_mfma_f32_32x32x16_bf16(vv[0], pa0.v, o0, 0, 0, 0);
        o0 = __builtin_amdgcn_mfma_f32_32x32x16_bf16(vv[1], pa1.v, o0, 0, 0, 0);
        o1 = __builtin_amdgcn_mfma_f32_32x32x16_bf16(vv[2], pa0.v, o1, 0, 0, 0);
        o1 = __builtin_amdgcn_mfma_f32_32x32x16_bf16(vv[3], pa1.v, o1, 0, 0, 0);
        o2 = __builtin_amdgcn_mfma_f32_32x32x16_bf16(vv[4], pa0.v, o2, 0, 0, 0);
        o2 = __builtin_amdgcn_mfma_f32_32x32x16_bf16(vv[5], pa1.v, o2, 0, 0, 0);
        o3 = __builtin_amdgcn_mfma_f32_32x32x16_bf16(vv[6], pa0.v, o3, 0, 0, 0);
        o3 = __builtin_amdgcn_mfma_f32_32x32x16_bf16(vv[7], pa1.v, o3, 0, 0, 0);
        __builtin_amdgcn_s_setprio(0);
    }

    // ---- merge seg1 -> seg0 through LDS ----
    __syncthreads();
    float* Mh = &Mrg[hd4][0];
    if (seg == 1) {
        #pragma unroll
        for (int r = 0; r < 16; ++r) {
            Mh[(0 * 16 + r) * 64 + lane] = o0[r];
            Mh[(1 * 16 + r) * 64 + lane] = o1[r];
            Mh[(2 * 16 + r) * 64 + lane] = o2[r];
            Mh[(3 * 16 + r) * 64 + lane] = o3[r];
        }
        Mh[4096 + lane] = m;
        Mh[4160 + lane] = s;
    }
    __syncthreads();
    if (seg == 0) {
        float m1 = Mh[4096 + lane], s1 = Mh[4160 + lane];
        float mn = fmaxf(m, m1);
        float ca = exp2f(m - mn), cb = exp2f(m1 - mn);
        s = s * ca + s1 * cb;
        #pragma unroll
        for (int r = 0; r < 16; ++r) {
            o0[r] = o0[r] * ca + Mh[(0 * 16 + r) * 64 + lane] * cb;
            o1[r] = o1[r] * ca + Mh[(1 * 16 + r) * 64 + lane] * cb;
            o2[r] = o2[r] * ca + Mh[(2 * 16 + r) * 64 + lane] * cb;
            o3[r] = o3[r] * ca + Mh[(3 * 16 + r) * 64 + lane] * cb;
        }
        float inv = 1.0f / s;
        __hip_bfloat16* yrow = yb + ((size_t)b * T_ + qa + l31) * D_ + h * HD_;
        #define WRITE_DB(ON, DB)                                                        \
            _Pragma("unroll")                                                           \
            for (int r4 = 0; r4 < 4; ++r4) {                                            \
                ushort4 u;                                                              \
                __hip_bfloat16 e0 = __float2bfloat16(ON[4*r4+0] * inv);                 \
                __hip_bfloat16 e1 = __float2bfloat16(ON[4*r4+1] * inv);                 \
                __hip_bfloat16 e2 = __float2bfloat16(ON[4*r4+2] * inv);                 \
                __hip_bfloat16 e3 = __float2bfloat16(ON[4*r4+3] * inv);                 \
                u.x = *(const unsigned short*)&e0; u.y = *(const unsigned short*)&e1;   \
                u.z = *(const unsigned short*)&e2; u.w = *(const unsigned short*)&e3;   \
                *(ushort4*)(yrow + (DB) * 32 + 8 * r4 + 4 * hi) = u;                    \
            }
        WRITE_DB(o0, 0) WRITE_DB(o1, 1) WRITE_DB(o2, 2) WRITE_DB(o3, 3)
        #undef WRITE_DB
    }
}

extern "C" void kernel_launch(void* const* d_in, const int* in_sizes, int n_in,
                              void* d_out, int out_size, void* d_ws, size_t ws_size,
                              hipStream_t stream) {
    (void)in_sizes; (void)n_in; (void)out_size; (void)ws_size;
    const float* x  = (const float*)d_in[0];
    const float* wq = (const float*)d_in[1];
    const float* wk = (const float*)d_in[2];
    const float* wv = (const float*)d_in[3];
    const float* wp = (const float*)d_in[4];
    const float* qg = (const float*)d_in[5];
    float* out = (float*)d_out;

    char* ws = (char*)d_ws;
    size_t off = 0;
    auto alloc = [&](size_t bytes) { char* p = ws + off; off += (bytes + 255) & ~(size_t)255; return p; };

    __hip_bfloat16* xb  = (__hip_bfloat16*)alloc((size_t)BT_ * D_ * 2);
    __hip_bfloat16* wqb = (__hip_bfloat16*)alloc((size_t)D_ * D_ * 2);
    __hip_bfloat16* wkb = (__hip_bfloat16*)alloc((size_t)KD_ * D_ * 2);
    __hip_bfloat16* wvb = (__hip_bfloat16*)alloc((size_t)KD_ * D_ * 2);
    __hip_bfloat16* wpb = (__hip_bfloat16*)alloc((size_t)D_ * D_ * 2);
    __hip_bfloat16* qbb = (__hip_bfloat16*)alloc((size_t)BT_ * D_ * 2);
    __hip_bfloat16* kfb = (__hip_bfloat16*)alloc((size_t)BT_ * KD_ * 2);  // K fragments
    __hip_bfloat16* vfb = (__hip_bfloat16*)alloc((size_t)BT_ * KD_ * 2);  // V fragments
    // alias (lifetimes disjoint on the sequential stream):
    __hip_bfloat16* ybb = xb;                   // yb written after xb's last read (gemm_qkv)

    f2b_all<<<2048, 256, 0, stream>>>((const float4*)x, (const float4*)wq, (const float4*)wk,
                                      (const float4*)wv, (const float4*)wp,
                                      (ushort4*)xb, (ushort4*)wqb, (ushort4*)wkb,
                                      (ushort4*)wvb, (ushort4*)wpb);

    // fused q/k/v projections + norm/rope/gain/layout epilogue
    dim3 gqkv(BT_ / 128, 24);
    gemm_qkv<<<gqkv, 256, 0, stream>>>(xb, wqb, wkb, wvb, qg, qbb, kfb, vfb);

    attn_fwd<<<512, 512, 0, stream>>>(qbb, kfb, vfb, ybb);

    // output projection
    dim3 gp(BT_ / 128, D_ / 128);
    gemm_p<<<gp, 256, 0, stream>>>(ybb, wpb, out, D_, D_);
}

// Round 19
// 195.671 us; speedup vs baseline: 1.0499x; 1.0499x over previous
//
#include <hip/hip_runtime.h>
#include <hip/hip_bf16.h>

#define B_   2
#define T_   2048
#define D_   2048
#define NH_  16
#define NKV_ 4
#define HD_  128
#define KD_  512   // NKV*HD
#define BT_  4096  // B_*T_

typedef __bf16 bf16x8 __attribute__((ext_vector_type(8)));
typedef float  f32x4  __attribute__((ext_vector_type(4)));
typedef float  f32x16 __attribute__((ext_vector_type(16)));

__device__ __forceinline__ void gload_lds16(const __hip_bfloat16* g, __hip_bfloat16* l) {
    __builtin_amdgcn_global_load_lds(
        (__attribute__((address_space(1))) void*)(g),
        (__attribute__((address_space(3))) void*)(l),
        16, 0, 0);
}

// ---------------- fp32 -> bf16 convert (all 5 tensors, one launch) ----------------
__global__ void f2b_all(const float4* __restrict__ x,  const float4* __restrict__ wq,
                        const float4* __restrict__ wk, const float4* __restrict__ wv,
                        const float4* __restrict__ wp,
                        ushort4* __restrict__ xb,  ushort4* __restrict__ wqb,
                        ushort4* __restrict__ wkb, ushort4* __restrict__ wvb,
                        ushort4* __restrict__ wpb) {
    const int e0 = BT_ * D_ / 4;
    const int e1 = e0 + D_ * D_ / 4;
    const int e2 = e1 + KD_ * D_ / 4;
    const int e3 = e2 + KD_ * D_ / 4;
    const int e4 = e3 + D_ * D_ / 4;
    int idx = blockIdx.x * blockDim.x + threadIdx.x;
    int stride = gridDim.x * blockDim.x;
    for (int j = idx; j < e4; j += stride) {
        const float4* src; ushort4* dst; int off;
        if      (j < e0) { src = x;  dst = xb;  off = j; }
        else if (j < e1) { src = wq; dst = wqb; off = j - e0; }
        else if (j < e2) { src = wk; dst = wkb; off = j - e1; }
        else if (j < e3) { src = wv; dst = wvb; off = j - e2; }
        else             { src = wp; dst = wpb; off = j - e3; }
        float4 v = src[off];
        __hip_bfloat16 a = __float2bfloat16(v.x), b = __float2bfloat16(v.y),
                       c = __float2bfloat16(v.z), d = __float2bfloat16(v.w);
        ushort4 o;
        o.x = *(const unsigned short*)&a; o.y = *(const unsigned short*)&b;
        o.z = *(const unsigned short*)&c; o.w = *(const unsigned short*)&d;
        dst[off] = o;
    }
}

// ====== pipelined 128x128 GEMM main loop (depth-2 counted vmcnt, 3 LDS slots) ======
// RACE FIX (rule #18 / m152): end-of-iter barrier is a real LDS fence
// (lgkmcnt(0) + sched_barrier before s_barrier) so ds_reads can't sink past it.
#define GEMM_PIPE(Aptr, Bptr, ROWB, colL, K)                                                  \
    const int tid = threadIdx.x, w = tid >> 6, lane = tid & 63;                               \
    const int lr = lane & 15, lk = lane >> 4;                                                 \
    const int wr = w >> 1, wc = w & 1;                                                        \
    const int lksw = lk ^ (lr & 3);                                                           \
    const size_t row0 = (size_t)(ROWB) * 128;                                                 \
    const int schunk = (tid % 4) ^ ((tid / 4) & 3);                                           \
    const __hip_bfloat16* ga = (Aptr) + (row0 + tid / 4) * (K) + schunk * 8;                  \
    const __hip_bfloat16* gb = (Bptr) + ((size_t)(colL) + tid / 4) * (K) + schunk * 8;        \
    const int KI = (K) >> 5;                                                                  \
    auto stage = [&](int u, int slot) {                                                       \
        int uu = u < KI ? u : KI - 1;                                                         \
        const int kk = uu * 32;                                                               \
        gload_lds16(ga + kk,                  &As[slot][w * 512]);                            \
        gload_lds16(ga + kk + (size_t)64*(K), &As[slot][2048 + w * 512]);                     \
        gload_lds16(gb + kk,                  &Bs[slot][w * 512]);                            \
        gload_lds16(gb + kk + (size_t)64*(K), &Bs[slot][2048 + w * 512]);                     \
    };                                                                                        \
    f32x4 acc[4][4] = {};                                                                     \
    stage(0, 0); stage(1, 1);                                                                 \
    int sstage = 2, scomp = 0;                                                                \
    for (int kt = 0; kt < KI; ++kt) {                                                         \
        stage(kt + 2, sstage);                                                                \
        asm volatile("s_waitcnt vmcnt(8)" ::: "memory");                                      \
        __builtin_amdgcn_s_barrier();                                                         \
        __builtin_amdgcn_sched_barrier(0);                                                    \
        bf16x8 af[4], bfr[4];                                                                 \
        _Pragma("unroll")                                                                     \
        for (int m = 0; m < 4; m++)                                                           \
            af[m] = *(const bf16x8*)&As[scomp][(wr * 64 + m * 16 + lr) * 32 + lksw * 8];      \
        _Pragma("unroll")                                                                     \
        for (int n = 0; n < 4; n++)                                                           \
            bfr[n] = *(const bf16x8*)&Bs[scomp][(wc * 64 + n * 16 + lr) * 32 + lksw * 8];     \
        _Pragma("unroll")                                                                     \
        for (int m = 0; m < 4; m++)                                                           \
            _Pragma("unroll")                                                                 \
            for (int n = 0; n < 4; n++)                                                       \
                acc[m][n] = __builtin_amdgcn_mfma_f32_16x16x32_bf16(af[m], bfr[n],            \
                                                                    acc[m][n], 0, 0, 0);      \
        asm volatile("s_waitcnt lgkmcnt(0)" ::: "memory");  /* LDS reads fully done */        \
        __builtin_amdgcn_sched_barrier(0);                                                    \
        __builtin_amdgcn_s_barrier();   /* end-of-iter: slot scomp now reusable */            \
        sstage = (sstage == 2) ? 0 : sstage + 1;                                              \
        scomp  = (scomp  == 2) ? 0 : scomp  + 1;                                              \
    }

// Fused q/k/v projection + RMSNorm + RoPE + gain + bf16 + fragment layouts.
__global__ __launch_bounds__(256, 3)
void gemm_qkv(const __hip_bfloat16* __restrict__ A,
              const __hip_bfloat16* __restrict__ Wq, const __hip_bfloat16* __restrict__ Wk,
              const __hip_bfloat16* __restrict__ Wv, const float* __restrict__ qg,
              __hip_bfloat16* __restrict__ qbb, __hip_bfloat16* __restrict__ kfb,
              __hip_bfloat16* __restrict__ vfb) {
    __shared__ __attribute__((aligned(16))) __hip_bfloat16 As[3][4096];
    __shared__ __attribute__((aligned(16))) __hip_bfloat16 Bs[3][4096];
    const int cb   = blockIdx.y;                  // 0..23: col-block (head)
    const int rowb = blockIdx.x;                  // 0..31: row-block
    const __hip_bfloat16* Bw;
    if (cb < 16)      Bw = Wq + (size_t)cb * 128 * D_;
    else if (cb < 20) Bw = Wk + (size_t)(cb - 16) * 128 * D_;
    else              Bw = Wv + (size_t)(cb - 20) * 128 * D_;

    GEMM_PIPE(A, Bw, rowb, 0, D_)

    // drain trailing staging DMAs before reusing As as the reduction buffer
    asm volatile("s_waitcnt vmcnt(0)" ::: "memory");
    __syncthreads();
    float* Red = (float*)&As[0][0];   // [2][128] partial sums

    if (cb < 20) {
        // ---- RMSNorm: row sum of squares over 128 cols ----
        float ssp[16];
        #pragma unroll
        for (int m = 0; m < 4; m++)
            #pragma unroll
            for (int r = 0; r < 4; r++) {
                float v = 0.f;
                #pragma unroll
                for (int n = 0; n < 4; n++) v += acc[m][n][r] * acc[m][n][r];
                #pragma unroll
                for (int off = 1; off < 16; off <<= 1) v += __shfl_xor(v, off);
                ssp[m * 4 + r] = v;
            }
        if (lr == 0) {
            #pragma unroll
            for (int m = 0; m < 4; m++)
                #pragma unroll
                for (int r = 0; r < 4; r++)
                    Red[wc * 128 + wr * 64 + m * 16 + lk * 4 + r] = ssp[m * 4 + r];
        }
        __syncthreads();
        #pragma unroll
        for (int m = 0; m < 4; m++)
            #pragma unroll
            for (int r = 0; r < 4; r++) {
                float tot = ssp[m * 4 + r] + Red[(wc ^ 1) * 128 + wr * 64 + m * 16 + lk * 4 + r];
                float rn = rsqrtf(tot * (1.0f / HD_) + 1.1920929e-7f);
                #pragma unroll
                for (int n = 0; n < 4; n++) acc[m][n][r] *= rn;
            }
        // ---- partial RoPE on dims 0..15 (cols 0..15 live in wc==0, n==0, d=lr) ----
        if (wc == 0) {
            float invf = exp2f(-(float)(lr & 7) * 1.66096404744368f);
            #pragma unroll
            for (int m = 0; m < 4; m++)
                #pragma unroll
                for (int r = 0; r < 4; r++) {
                    int t = (int)((row0 + wr * 64 + m * 16 + lk * 4 + r) & (T_ - 1));
                    float f = (float)t * invf;
                    float sn, cs;
                    sincosf(f, &sn, &cs);
                    float y  = acc[m][0][r];
                    float yp = __shfl_xor(y, 8);
                    acc[m][0][r] = (lr < 8) ? (y * cs + yp * sn) : (-y * cs + yp * sn);
                }
        }
    }

    if (cb < 16) {
        // q: gain * 1/sqrt(HD) * log2(e), layout [b][h][t][hd]
        float g = qg[cb] * 0.1275174305f;
        #pragma unroll
        for (int m = 0; m < 4; m++)
            #pragma unroll
            for (int r = 0; r < 4; r++) {
                size_t bt = row0 + wr * 64 + m * 16 + lk * 4 + r;
                int b = (int)(bt >> 11), t = (int)(bt & (T_ - 1));
                __hip_bfloat16* dst = qbb + ((size_t)(b * NH_ + cb) * T_ + t) * HD_;
                #pragma unroll
                for (int n = 0; n < 4; n++) {
                    int d = wc * 64 + n * 16 + lr;
                    dst[d] = __float2bfloat16(acc[m][n][r] * g);
                }
            }
    } else if (cb < 20) {
        // k: fragment layout  ((t>>5)*8+(d>>4))*2+((d>>3)&1))*256 + (t&31)*8 + (d&7)
        int kv = cb - 16;
        #pragma unroll
        for (int m = 0; m < 4; m++)
            #pragma unroll
            for (int r = 0; r < 4; r++) {
                size_t bt = row0 + wr * 64 + m * 16 + lk * 4 + r;
                int b = (int)(bt >> 11), t = (int)(bt & (T_ - 1));
                __hip_bfloat16* base = kfb + (size_t)(b * NKV_ + kv) * T_ * HD_;
                #pragma unroll
                for (int n = 0; n < 4; n++) {
                    int d = wc * 64 + n * 16 + lr;
                    size_t idx2 = (size_t)((((t >> 5) * 8 + (d >> 4)) * 2 + ((d >> 3) & 1))) * 256
                               + (t & 31) * 8 + (d & 7);
                    base[idx2] = __float2bfloat16(acc[m][n][r]);
                }
            }
    } else {
        // v: fragment layout  ((((t>>5)*4+(d>>5))*4+((t>>3)&3))*32+(d&31))*8 + (t&7)
        int kv = cb - 20;
        #pragma unroll
        for (int m = 0; m < 4; m++)
            #pragma unroll
            for (int r = 0; r < 4; r++) {
                size_t bt = row0 + wr * 64 + m * 16 + lk * 4 + r;
                int b = (int)(bt >> 11), t = (int)(bt & (T_ - 1));
                __hip_bfloat16* base = vfb + (size_t)(b * NKV_ + kv) * T_ * HD_;
                #pragma unroll
                for (int n = 0; n < 4; n++) {
                    int d = wc * 64 + n * 16 + lr;
                    size_t idx2 = (size_t)(((((t >> 5) * 4 + (d >> 5)) * 4 + ((t >> 3) & 3)) * 32
                               + (d & 31))) * 8 + (t & 7);
                    base[idx2] = __float2bfloat16(acc[m][n][r]);
                }
            }
    }
}

// Plain pipelined GEMM (output projection), f32 out
__global__ __launch_bounds__(256, 3)
void gemm_p(const __hip_bfloat16* __restrict__ A, const __hip_bfloat16* __restrict__ B,
            float* __restrict__ C, int N, int K) {
    __shared__ __attribute__((aligned(16))) __hip_bfloat16 As[3][4096];
    __shared__ __attribute__((aligned(16))) __hip_bfloat16 Bs[3][4096];
    const int colL = blockIdx.y * 128;
    GEMM_PIPE(A, B, blockIdx.x, colL, K)
    #pragma unroll
    for (int m = 0; m < 4; m++)
        #pragma unroll
        for (int n = 0; n < 4; n++)
            #pragma unroll
            for (int r = 0; r < 4; r++)
                C[(row0 + wr * 64 + m * 16 + lk * 4 + r) * (size_t)N
                  + colL + wc * 64 + n * 16 + lr] = acc[m][n][r];
}

// ---------------- causal GQA flash attention ----------------
// UNIFORM blocks: grid 256 = 8 streams x 32; block = 4 heads x 2 KV-segments,
// processes TWO chunks sequentially (c = 63-2i then c = 2i) -> every block runs
// exactly 33 tile-iterations. 1 block/CU: no dispatch-pairing assumptions.
// No in-loop barrier (loop touches no LDS) -> 8 waves free-run and interleave.
// Dead-segment safety: fully-dead seg keeps m=-1e30 -> merge weight 0;
// tail-dead tiles give p=exp2(-inf)=0.
__device__ __forceinline__ unsigned pkbf(float a, float b) {
    __hip_bfloat16 x = __float2bfloat16(a), y = __float2bfloat16(b);
    unsigned short xu = *(const unsigned short*)&x, yu = *(const unsigned short*)&y;
    return (unsigned)xu | ((unsigned)yu << 16);
}

union U8u { unsigned u[4]; bf16x8 v; };

__global__ __launch_bounds__(512, 2)
void attn_fwd(const __hip_bfloat16* __restrict__ qb, const __hip_bfloat16* __restrict__ kfb,
              const __hip_bfloat16* __restrict__ vfb, __hip_bfloat16* __restrict__ yb) {
    __shared__ float Mrg[4][4224];   // per-head merge region: 4096 O + 64 m + 64 s
    const int tid  = threadIdx.x;
    const int w    = tid >> 6, lane = tid & 63;
    const int l31  = lane & 31, hi = lane >> 5;
    const int hd4  = w & 3;                // head within kv group
    const int seg  = w >> 2;               // KV segment 0/1
    const int bid  = blockIdx.x;
    const int strm = bid & 7;              // = b*4 + kvh (XCD-grouped K/V stream)
    const int b    = strm >> 2, kvh = strm & 3;
    const int i    = bid >> 3;             // 0..31
    const int h    = kvh * 4 + hd4;

    const __hip_bfloat16* kfp = kfb + (size_t)(b * NKV_ + kvh) * T_ * HD_ + lane * 8;
    const __hip_bfloat16* vfp = vfb + (size_t)(b * NKV_ + kvh) * T_ * HD_ + lane * 8;

    #pragma unroll
    for (int ph = 0; ph < 2; ++ph) {
        const int c  = (ph == 0) ? (63 - 2 * i) : (2 * i);
        const int ns = (c >> 1) + 1;       // iters per segment
        const int qa = c * 32;

        const __hip_bfloat16* qp = qb + ((size_t)(b * NH_ + h) * T_ + qa) * HD_;
        bf16x8 qfr[8];
        #pragma unroll
        for (int hb = 0; hb < 8; ++hb)
            qfr[hb] = *(const bf16x8*)(qp + (size_t)l31 * HD_ + hb * 16 + hi * 8);

        f32x16 o0 = {}, o1 = {}, o2 = {}, o3 = {};
        float m = -1e30f, s = 0.f;

        bf16x8 kk[8], vv[8];
        {   // prologue: K fragments of this segment's first tile
            int kt0 = seg ? (ns <= c ? ns : c) : 0;
            #pragma unroll
            for (int hb = 0; hb < 8; ++hb)
                kk[hb] = *(const bf16x8*)(kfp + ((size_t)kt0 * 16 + hb * 2) * 256);
        }

        for (int t = 0; t < ns; ++t) {
            const int kt_raw = seg ? ns + t : t;
            const bool dead  = kt_raw > c;
            const int kt     = dead ? c : kt_raw;

            // V(kt) fragment loads issued early (consumed after QK+softmax)
            #pragma unroll
            for (int db = 0; db < 4; ++db) {
                vv[db * 2]     = *(const bf16x8*)(vfp + ((size_t)kt * 16 + db * 4) * 256);
                vv[db * 2 + 1] = *(const bf16x8*)(vfp + ((size_t)kt * 16 + db * 4) * 256 + 512);
            }

            // S^T[kv][q] = sum_hd K[kv][hd] * Q[q][hd]  (two independent 4-chains)
            f32x16 sa_a = {}, sa_b = {};
            __builtin_amdgcn_s_setprio(1);
            #pragma unroll
            for (int hb = 0; hb < 4; ++hb)
                sa_a = __builtin_amdgcn_mfma_f32_32x32x16_bf16(kk[hb], qfr[hb], sa_a, 0, 0, 0);
            #pragma unroll
            for (int hb = 4; hb < 8; ++hb)
                sa_b = __builtin_amdgcn_mfma_f32_32x32x16_bf16(kk[hb], qfr[hb], sa_b, 0, 0, 0);
            __builtin_amdgcn_s_setprio(0);
            f32x16 sa = sa_a + sa_b;

            // prefetch next K tile (hidden under softmax + PV)
            {
                int ktn = seg * 0 + (seg ? ns : 0) + t + 1; if (ktn > c) ktn = c;
                #pragma unroll
                for (int hb = 0; hb < 8; ++hb)
                    kk[hb] = *(const bf16x8*)(kfp + ((size_t)ktn * 16 + hb * 2) * 256);
            }

            if (dead) {
                #pragma unroll
                for (int r = 0; r < 16; ++r) sa[r] = -1e30f;
            } else if (kt == c) {  // diagonal tile: mask kv > q (relative indices)
                #pragma unroll
                for (int r = 0; r < 16; ++r) {
                    int kvrel = (r & 3) + 8 * (r >> 2) + 4 * hi;
                    if (kvrel > l31) sa[r] = -1e30f;
                }
            }
            float pm = sa[0];
            #pragma unroll
            for (int r = 1; r < 16; ++r) pm = fmaxf(pm, sa[r]);
            pm = fmaxf(pm, __shfl_xor(pm, 32));
            if (!__all(pm <= m + 8.f)) {   // deferred rescale (THR=8, log2 domain)
                float mn = fmaxf(m, pm);
                float corr = exp2f(m - mn);
                s *= corr;
                #pragma unroll
                for (int r = 0; r < 16; ++r) { o0[r] *= corr; o1[r] *= corr; o2[r] *= corr; o3[r] *= corr; }
                m = mn;
            }
            float p[16]; float rs = 0.f;
            #pragma unroll
            for (int r = 0; r < 16; ++r) { p[r] = exp2f(sa[r] - m); rs += p[r]; }
            rs += __shfl_xor(rs, 32);
            s += rs;
            // pack P -> bf16 PV B-fragments (lane pair l <-> l^32 exchange)
            unsigned pk[8];
            #pragma unroll
            for (int jj = 0; jj < 8; ++jj) pk[jj] = pkbf(p[2 * jj], p[2 * jj + 1]);
            unsigned pks[8];
            #pragma unroll
            for (int jj = 0; jj < 8; ++jj) pks[jj] = (unsigned)__shfl_xor((int)pk[jj], 32);
            U8u pa0, pa1;
            pa0.u[0] = hi ? pks[2] : pk[0];
            pa0.u[1] = hi ? pks[3] : pk[1];
            pa0.u[2] = hi ? pk[2]  : pks[0];
            pa0.u[3] = hi ? pk[3]  : pks[1];
            pa1.u[0] = hi ? pks[6] : pk[4];
            pa1.u[1] = hi ? pks[7] : pk[5];
            pa1.u[2] = hi ? pk[6]  : pks[4];
            pa1.u[3] = hi ? pk[7]  : pks[5];
            // O^T[d][q] += V^T[d][kv] * P[kv][q]
            __builtin_amdgcn_s_setprio(1);
            o0 = __builtin_amdgcn_mfma_f32_32x32x16_bf16(vv[0], pa0.v, o0, 0, 0, 0);
            o0 = __builtin_amdgcn_mfma_f32_32x32x16_bf16(vv[1], pa1.v, o0, 0, 0, 0);
            o1 = __builtin_amdgcn_mfma_f32_32x32x16_bf16(vv[2], pa0.v, o1, 0, 0, 0);
            o1 = __builtin_amdgcn_mfma_f32_32x32x16_bf16(vv[3], pa1.v, o1, 0, 0, 0);
            o2 = __builtin_amdgcn_mfma_f32_32x32x16_bf16(vv[4], pa0.v, o2, 0, 0, 0);
            o2 = __builtin_amdgcn_mfma_f32_32x32x16_bf16(vv[5], pa1.v, o2, 0, 0, 0);
            o3 = __builtin_amdgcn_mfma_f32_32x32x16_bf16(vv[6], pa0.v, o3, 0, 0, 0);
            o3 = __builtin_amdgcn_mfma_f32_32x32x16_bf16(vv[7], pa1.v, o3, 0, 0, 0);
            __builtin_amdgcn_s_setprio(0);
        }

        // ---- merge seg1 -> seg0 through LDS ----
        __syncthreads();                   // phase isolation: prev-phase reads done
        float* Mh = &Mrg[hd4][0];
        if (seg == 1) {
            #pragma unroll
            for (int r = 0; r < 16; ++r) {
                Mh[(0 * 16 + r) * 64 + lane] = o0[r];
                Mh[(1 * 16 + r) * 64 + lane] = o1[r];
                Mh[(2 * 16 + r) * 64 + lane] = o2[r];
                Mh[(3 * 16 + r) * 64 + lane] = o3[r];
            }
            Mh[4096 + lane] = m;
            Mh[4160 + lane] = s;
        }
        __syncthreads();
        if (seg == 0) {
            float m1 = Mh[4096 + lane], s1 = Mh[4160 + lane];
            float mn = fmaxf(m, m1);
            float ca = exp2f(m - mn), cb = exp2f(m1 - mn);
            s = s * ca + s1 * cb;
            #pragma unroll
            for (int r = 0; r < 16; ++r) {
                o0[r] = o0[r] * ca + Mh[(0 * 16 + r) * 64 + lane] * cb;
                o1[r] = o1[r] * ca + Mh[(1 * 16 + r) * 64 + lane] * cb;
                o2[r] = o2[r] * ca + Mh[(2 * 16 + r) * 64 + lane] * cb;
                o3[r] = o3[r] * ca + Mh[(3 * 16 + r) * 64 + lane] * cb;
            }
            float inv = 1.0f / s;
            __hip_bfloat16* yrow = yb + ((size_t)b * T_ + qa + l31) * D_ + h * HD_;
            #define WRITE_DB(ON, DB)                                                        \
                _Pragma("unroll")                                                           \
                for (int r4 = 0; r4 < 4; ++r4) {                                            \
                    ushort4 u;                                                              \
                    __hip_bfloat16 e0 = __float2bfloat16(ON[4*r4+0] * inv);                 \
                    __hip_bfloat16 e1 = __float2bfloat16(ON[4*r4+1] * inv);                 \
                    __hip_bfloat16 e2 = __float2bfloat16(ON[4*r4+2] * inv);                 \
                    __hip_bfloat16 e3 = __float2bfloat16(ON[4*r4+3] * inv);                 \
                    u.x = *(const unsigned short*)&e0; u.y = *(const unsigned short*)&e1;   \
                    u.z = *(const unsigned short*)&e2; u.w = *(const unsigned short*)&e3;   \
                    *(ushort4*)(yrow + (DB) * 32 + 8 * r4 + 4 * hi) = u;                    \
                }
            WRITE_DB(o0, 0) WRITE_DB(o1, 1) WRITE_DB(o2, 2) WRITE_DB(o3, 3)
            #undef WRITE_DB
        }
    }
}

extern "C" void kernel_launch(void* const* d_in, const int* in_sizes, int n_in,
                              void* d_out, int out_size, void* d_ws, size_t ws_size,
                              hipStream_t stream) {
    (void)in_sizes; (void)n_in; (void)out_size; (void)ws_size;
    const float* x  = (const float*)d_in[0];
    const float* wq = (const float*)d_in[1];
    const float* wk = (const float*)d_in[2];
    const float* wv = (const float*)d_in[3];
    const float* wp = (const float*)d_in[4];
    const float* qg = (const float*)d_in[5];
    float* out = (float*)d_out;

    char* ws = (char*)d_ws;
    size_t off = 0;
    auto alloc = [&](size_t bytes) { char* p = ws + off; off += (bytes + 255) & ~(size_t)255; return p; };

    __hip_bfloat16* xb  = (__hip_bfloat16*)alloc((size_t)BT_ * D_ * 2);
    __hip_bfloat16* wqb = (__hip_bfloat16*)alloc((size_t)D_ * D_ * 2);
    __hip_bfloat16* wkb = (__hip_bfloat16*)alloc((size_t)KD_ * D_ * 2);
    __hip_bfloat16* wvb = (__hip_bfloat16*)alloc((size_t)KD_ * D_ * 2);
    __hip_bfloat16* wpb = (__hip_bfloat16*)alloc((size_t)D_ * D_ * 2);
    __hip_bfloat16* qbb = (__hip_bfloat16*)alloc((size_t)BT_ * D_ * 2);
    __hip_bfloat16* kfb = (__hip_bfloat16*)alloc((size_t)BT_ * KD_ * 2);  // K fragments
    __hip_bfloat16* vfb = (__hip_bfloat16*)alloc((size_t)BT_ * KD_ * 2);  // V fragments
    // alias (lifetimes disjoint on the sequential stream):
    __hip_bfloat16* ybb = xb;                   // yb written after xb's last read (gemm_qkv)

    f2b_all<<<2048, 256, 0, stream>>>((const float4*)x, (const float4*)wq, (const float4*)wk,
                                      (const float4*)wv, (const float4*)wp,
                                      (ushort4*)xb, (ushort4*)wqb, (ushort4*)wkb,
                                      (ushort4*)wvb, (ushort4*)wpb);

    // fused q/k/v projections + norm/rope/gain/layout epilogue
    dim3 gqkv(BT_ / 128, 24);
    gemm_qkv<<<gqkv, 256, 0, stream>>>(xb, wqb, wkb, wvb, qg, qbb, kfb, vfb);

    attn_fwd<<<256, 512, 0, stream>>>(qbb, kfb, vfb, ybb);

    // output projection
    dim3 gp(BT_ / 128, D_ / 128);
    gemm_p<<<gp, 256, 0, stream>>>(ybb, wpb, out, D_, D_);
}